// Round 11
// baseline (161.606 us; speedup 1.0000x reference)
//
#include <hip/hip_runtime.h>
#include <hip/hip_bf16.h>

// Segment-mean over N=2,000,000 sorted nodes -> G=16384 graphs, then linear.
// x: [N,64] f32, segment_ids: [N] int32 (sorted), weight: [128,64] f32,
// bias: [128] f32, out: [G,128] f32.  HBM-bound: ~520 MB read -> ~84 us floor.
//
// R11 = R3 (100.3/100.8 us) with ONLY the LDS W-tile removed (clean A/B on the
// block-retire-granularity theory):
//   - Same 512-thr block = 8 adjacent graphs (locality is load-bearing, R8).
//   - Same windowed search, same branch-free nt-float4 streamer, same butterfly.
//   - Epilogue reads W rows l, l+64 from GLOBAL (32 KB = L1-sized, all-hit
//     after warmup; proven correct in R8). No LDS, no barrier -> wave slots
//     free individually, new blocks launch fluidly instead of waiting for a
//     whole 33 KB-LDS block to retire (E[max-of-8] ~ +13% = the ~13 us gap).

#define IN_CH 64
#define OUT_CH 128
#define WPB 8               // waves (= graphs) per block
#define BLOCK (WPB * 64)    // 512 threads

typedef float f32x4 __attribute__((ext_vector_type(4)));

__device__ __forceinline__ f32x4 ntload(const float* p) {
    return __builtin_nontemporal_load(reinterpret_cast<const f32x4*>(p));
}

__global__ __launch_bounds__(BLOCK) void fused_nolds512_kernel(
        const float* __restrict__ x, const int* __restrict__ ids,
        const float* __restrict__ W, const float* __restrict__ bias,
        float* __restrict__ out, int N, int G) {
    const int t  = threadIdx.x;
    const int wv = t >> 6;        // wave in block 0..7
    const int l  = t & 63;        // lane
    const int g  = blockIdx.x * WPB + wv;
    if (g >= G) return;

    // ---- Per-wave range search (identical to R3): even lanes target g, odd
    // lanes g+1; validated +-4096 window, full-range fallback -> correct for
    // ANY sorted input.
    const int target = g + (l & 1);
    int lo = 0, hi = N;
    {
        const int guess = (int)(((long long)target * (long long)N) / (long long)G);
        int wlo = guess - 4096; if (wlo < 0) wlo = 0;
        int whi = guess + 4096; if (whi > N) whi = N;
        const bool ok_lo = (wlo == 0) || (ids[wlo - 1] < target);
        const bool ok_hi = (whi == N) || (ids[whi] >= target);
        if (ok_lo && ok_hi) { lo = wlo; hi = whi; }
        while (lo < hi) {
            const int mid = (lo + hi) >> 1;
            if (ids[mid] < target) lo = mid + 1; else hi = mid;
        }
    }
    const int s0 = __shfl(lo, 0);
    const int s1 = __shfl(lo, 1);

    const int rs = l >> 4;              // row stream 0..3
    const int cq = (l & 15) << 2;       // channel quad base

    // ---- Stream the segment (identical to R3): 8 rows / iter, two 1 KiB
    // wave-loads in flight, nontemporal (x is read-once).
    float4 a0 = make_float4(0.f, 0.f, 0.f, 0.f);
    float4 a1 = make_float4(0.f, 0.f, 0.f, 0.f);
    int r = s0;
    for (; r + 8 <= s1; r += 8) {
        const f32x4 v0 = ntload(x + (size_t)(r + rs)     * IN_CH + cq);
        const f32x4 v1 = ntload(x + (size_t)(r + 4 + rs) * IN_CH + cq);
        a0.x += v0.x; a0.y += v0.y; a0.z += v0.z; a0.w += v0.w;
        a1.x += v1.x; a1.y += v1.y; a1.z += v1.z; a1.w += v1.w;
    }
    if (r + 4 <= s1) {
        const f32x4 v = ntload(x + (size_t)(r + rs) * IN_CH + cq);
        a0.x += v.x; a0.y += v.y; a0.z += v.z; a0.w += v.w;
        r += 4;
    }
    if (r + rs < s1) {
        const f32x4 v = ntload(x + (size_t)(r + rs) * IN_CH + cq);
        a1.x += v.x; a1.y += v.y; a1.z += v.z; a1.w += v.w;
    }

    float sx = a0.x + a1.x;
    float sy = a0.y + a1.y;
    float sz = a0.z + a1.z;
    float sw = a0.w + a1.w;

    // Butterfly over the 4 row streams (identical to R3).
    sx += __shfl_xor(sx, 16); sy += __shfl_xor(sy, 16);
    sz += __shfl_xor(sz, 16); sw += __shfl_xor(sw, 16);
    sx += __shfl_xor(sx, 32); sy += __shfl_xor(sy, 32);
    sz += __shfl_xor(sz, 32); sw += __shfl_xor(sw, 32);

    const float cnt = (float)(s1 - s0);
    const float m0 = sx / cnt;
    const float m1 = sy / cnt;
    const float m2 = sz / cnt;
    const float m3 = sw / cnt;

    // ---- Epilogue (from R8, proven correct): out[g][l], out[g][l+64] from
    // global W rows l, l+64 (L1-resident). Mean channels c4..c4+3 live in
    // lane (c4>>2) components 0..3; compile-time-lane __shfl -> v_readlane.
    const float* w0 = W + (size_t)l        * IN_CH;
    const float* w1 = W + (size_t)(l + 64) * IN_CH;
    float o0 = bias[l];
    float o1 = bias[l + 64];
    #pragma unroll
    for (int c4 = 0; c4 < IN_CH; c4 += 4) {
        const f32x4 wa = *reinterpret_cast<const f32x4*>(w0 + c4);
        const f32x4 wb = *reinterpret_cast<const f32x4*>(w1 + c4);
        const int   src = c4 >> 2;
        const float mm0 = __shfl(m0, src);
        const float mm1 = __shfl(m1, src);
        const float mm2 = __shfl(m2, src);
        const float mm3 = __shfl(m3, src);
        o0 = fmaf(wa.x, mm0, o0); o0 = fmaf(wa.y, mm1, o0);
        o0 = fmaf(wa.z, mm2, o0); o0 = fmaf(wa.w, mm3, o0);
        o1 = fmaf(wb.x, mm0, o1); o1 = fmaf(wb.y, mm1, o1);
        o1 = fmaf(wb.z, mm2, o1); o1 = fmaf(wb.w, mm3, o1);
    }
    out[(size_t)g * OUT_CH + l]      = o0;
    out[(size_t)g * OUT_CH + l + 64] = o1;
}

extern "C" void kernel_launch(void* const* d_in, const int* in_sizes, int n_in,
                              void* d_out, int out_size, void* d_ws, size_t ws_size,
                              hipStream_t stream) {
    const float* x    = (const float*)d_in[0];
    const int*   ids  = (const int*)d_in[1];
    const float* W    = (const float*)d_in[2];
    const float* bias = (const float*)d_in[3];
    float* out = (float*)d_out;

    const int N = in_sizes[1];             // 2,000,000
    const int G = out_size / OUT_CH;       // 16384

    const int blocks = (G + WPB - 1) / WPB;   // 2048
    fused_nolds512_kernel<<<blocks, BLOCK, 0, stream>>>(
        x, ids, W, bias, out, N, G);
}